// Round 14
// baseline (150.605 us; speedup 1.0000x reference)
//
#include <hip/hip_runtime.h>
#include <hip/hip_bf16.h>
#include <stdint.h>

typedef __bf16 bf16x8 __attribute__((ext_vector_type(8)));
typedef __bf16 bf16x4 __attribute__((ext_vector_type(4)));
typedef float f32x4 __attribute__((ext_vector_type(4)));

#define N_NODES 32
#define FDIM 256
#define N_TYPES 8
#define BT_TILE 32
#define TILES 16              // A-tiles per block
#define ROW_B (FDIM * 2)      // 512 B per LDS row (bf16)
#define K2_BLOCKS 512

// XOR swizzle: row stride 512B puts each k-column in one bank; (row&7)<<4
// spreads 16B slots across 8 positions. Applied on write and read.
__device__ __forceinline__ unsigned swz(unsigned byte_off, unsigned row) {
    return byte_off ^ ((row & 7u) << 4);
}
__device__ __forceinline__ void lds_dma16(void* lds, const void* g) {
    __builtin_amdgcn_global_load_lds(
        (const __attribute__((address_space(1))) unsigned int*)g,
        (__attribute__((address_space(3))) unsigned int*)lds, 16, 0, 0);
}

// ---------------------------------------------------------------------------
// k0: one-time W fp32->bf16, PRE-SWIZZLED full [256 o x 256 k] image per type
// so k1 stages it with linear global_load_lds. Image byte
// L = (o*512 + k*2) ^ ((o&7)<<4) holds W[t][o][k].
// ---------------------------------------------------------------------------
__global__ __launch_bounds__(256) void k0_convert_w(
    const float* __restrict__ w, __bf16* __restrict__ wp)
{
    int idx = blockIdx.x * 256 + threadIdx.x;   // [t][o][k]
    int t = idx >> 16, o = (idx >> 8) & 255, k = idx & 255;
    unsigned L = (unsigned)(o * ROW_B + k * 2) ^ ((o & 7u) << 4);
    wp[(size_t)t * (FDIM * FDIM) + (L >> 1)] = (__bf16)w[idx];
}

// ---------------------------------------------------------------------------
// k1: persistent-W GEMM, R4/R12-EXACT (bf16 epilogue, ~30us = 6.4 TB/s for
// its 192 MB -- at the BW ceiling; every fp32 epilogue measured 76-94us).
// Block = (n, bt-group of 512 rows). Full W[t] bf16 in LDS (128 KB, DMA'd
// once); 16 A-tiles [32 x 256], A double-buffered + reg-prefetched one tile
// ahead. Writes out1 bf16 into the FIRST 16 KB of each out[bt] 32KB slot,
// MFMA-frag-permuted: element (bt, n, p), p = wid*64 + lr*4 + nf, at byte
// bt*32768 + n*512 + p*2. 8B/lane contiguous stores. FROZEN.
// ---------------------------------------------------------------------------
__global__ __launch_bounds__(256, 1) void k1_node_gemm(
    const float* __restrict__ input, const __bf16* __restrict__ wp,
    const float* __restrict__ bias, const int* __restrict__ ntype,
    char* __restrict__ outb)
{
    __shared__ __bf16 sW[FDIM * FDIM];          // 131072 B
    __shared__ __bf16 sA[2][BT_TILE * FDIM];    // 2 x 16384 B  (total = 160 KiB)

    const int tid = threadIdx.x;
    const int n = blockIdx.x >> 3;
    const int base = (blockIdx.x & 7) * (TILES * BT_TILE);
    const int t = ntype[n];

    const int wid = tid >> 6, lane = tid & 63;
    const int lr = lane & 15, lq = lane >> 4;
    const int sr = tid >> 3;        // staging row 0..31
    const int sk = tid & 7;         // staging k-octet

    char* sWb = (char*)sW;
    char* sA0 = (char*)sA[0];
    char* sA1 = (char*)sA[1];

    // ---- prologue ----
    const char* wsrc = (const char*)(wp + (size_t)t * (FDIM * FDIM));
#pragma unroll
    for (int j = 0; j < 32; ++j)
        lds_dma16(sWb + j * 4096 + tid * 16, wsrc + j * 4096 + tid * 16);

    float bv[4];
#pragma unroll
    for (int nf = 0; nf < 4; ++nf)
        bv[nf] = bias[t * FDIM + wid * 64 + nf * 16 + lr];

    const char* Abase = (const char*)input
        + ((size_t)(base + sr) * (N_NODES * FDIM) + n * FDIM) * 4 + sk * 16;
    const size_t tile_stride = (size_t)BT_TILE * N_NODES * FDIM * 4;

    float4 av0[8], av1[8];
#pragma unroll
    for (int q = 0; q < 8; ++q)
        av0[q] = *reinterpret_cast<const float4*>(Abase + q * 128);
#pragma unroll
    for (int q = 0; q < 8; ++q)
        av1[q] = *reinterpret_cast<const float4*>(Abase + tile_stride + q * 128);

#pragma unroll
    for (int q = 0; q < 8; ++q) {   // cvt tile0 -> sA0
        bf16x4 h; h[0]=(__bf16)av0[q].x; h[1]=(__bf16)av0[q].y;
        h[2]=(__bf16)av0[q].z; h[3]=(__bf16)av0[q].w;
        *reinterpret_cast<bf16x4*>(sA0 + swz(sr * ROW_B + q * 64 + sk * 8, sr)) = h;
    }
    __syncthreads();   // drains W DMA + A(0) writes

    f32x4 acc[2][4];

#define COMPUTE_TILE(SBUF, TI)                                                  \
    {                                                                           \
        _Pragma("unroll")                                                       \
        for (int mf = 0; mf < 2; ++mf)                                          \
            _Pragma("unroll")                                                   \
            for (int nf = 0; nf < 4; ++nf)                                      \
                acc[mf][nf] = f32x4{0.f, 0.f, 0.f, 0.f};                        \
        _Pragma("unroll")                                                       \
        for (int ks = 0; ks < 8; ++ks) {                                        \
            const int kb = ks * 64 + lq * 16;                                   \
            bf16x8 af[2], bfv[4];                                               \
            _Pragma("unroll")                                                   \
            for (int mf = 0; mf < 2; ++mf) {                                    \
                int r = mf * 16 + lr;                                           \
                af[mf] = *reinterpret_cast<const bf16x8*>(                      \
                    SBUF + swz(r * ROW_B + kb, r));                             \
            }                                                                   \
            _Pragma("unroll")                                                   \
            for (int nf = 0; nf < 4; ++nf) {                                    \
                int o = wid * 64 + nf * 16 + lr;                                \
                bfv[nf] = *reinterpret_cast<const bf16x8*>(                     \
                    sWb + swz(o * ROW_B + kb, o));                              \
            }                                                                   \
            _Pragma("unroll")                                                   \
            for (int mf = 0; mf < 2; ++mf)                                      \
                _Pragma("unroll")                                               \
                for (int nf = 0; nf < 4; ++nf)                                  \
                    acc[mf][nf] = __builtin_amdgcn_mfma_f32_16x16x32_bf16(      \
                        af[mf], bfv[nf], acc[mf][nf], 0, 0, 0);                 \
        }                                                                       \
        /* epilogue: +bias, cvt bf16, frag-permuted coalesced store */          \
        _Pragma("unroll")                                                       \
        for (int mf = 0; mf < 2; ++mf)                                          \
            _Pragma("unroll")                                                   \
            for (int j = 0; j < 4; ++j) {                                       \
                bf16x4 h;                                                       \
                _Pragma("unroll")                                               \
                for (int nf = 0; nf < 4; ++nf)                                  \
                    h[nf] = (__bf16)(acc[mf][nf][j] + bv[nf]);                  \
                size_t bt = (size_t)(base + (TI) * BT_TILE + mf * 16 + lq * 4 + j); \
                *reinterpret_cast<bf16x4*>(outb + bt * 32768 + n * 512          \
                                           + wid * 128 + lr * 8) = h;           \
            }                                                                   \
    }

#define CVT_TO(AV, SDST)                                                        \
    {                                                                           \
        _Pragma("unroll")                                                       \
        for (int q = 0; q < 8; ++q) {                                           \
            bf16x4 h; h[0]=(__bf16)AV[q].x; h[1]=(__bf16)AV[q].y;               \
            h[2]=(__bf16)AV[q].z; h[3]=(__bf16)AV[q].w;                         \
            *reinterpret_cast<bf16x4*>(SDST + swz(sr * ROW_B + q * 64 + sk * 8, \
                                                  sr)) = h;                     \
        }                                                                       \
    }

#define LOAD_TILE(AV, TI)                                                       \
    {                                                                           \
        const char* rp = Abase + (size_t)(TI) * tile_stride;                    \
        _Pragma("unroll")                                                       \
        for (int q = 0; q < 8; ++q)                                             \
            AV[q] = *reinterpret_cast<const float4*>(rp + q * 128);             \
    }

    for (int tt = 0; tt < 8; ++tt) {
        const int e = 2 * tt;
        if (e + 2 < TILES) LOAD_TILE(av0, e + 2);
        COMPUTE_TILE(sA0, e);
        CVT_TO(av1, sA1);
        __syncthreads();
        const int od = 2 * tt + 1;
        if (od + 2 < TILES) LOAD_TILE(av1, od + 2);
        COMPUTE_TILE(sA1, od);
        if (tt < 7) {
            CVT_TO(av0, sA0);
            __syncthreads();
        }
    }
#undef COMPUTE_TILE
#undef CVT_TO
#undef LOAD_TILE
}

// ---------------------------------------------------------------------------
// k2: graph aggregation, in-place slot upgrade bf16 -> fp32.
// STRUCTURAL change (the one variable never varied): 512 PERSISTENT blocks
// x 8 slots each, software-pipelined, instead of 4096 single-slot blocks
// (every single-slot k2 = 49-55us across six read mechanisms; tiny blocks
// never reach steady state). Per iteration:
//   __syncthreads  -> vmcnt drain = all threads' reads of slot s complete
//                     (the in-place fence), and prior stores retired;
//   issue slot s+1's 32x2B gathers as RAW ushorts (no dependent cvt -> the
//                     latency hides under the compute below);
//   compute slot s (1024 FMA/thread, ~2048 cyc/wave) + dense fp32 stores.
// Read pattern per wave: 64x2B in a 128B window (R12-proven); stores 256B
// dense/wave full lines; g via uniform s_load (proven).
// ---------------------------------------------------------------------------
__global__ __launch_bounds__(256) void k2_graph_agg(
    char* __restrict__ outb, const float* __restrict__ g, int spb)
{
    const int tid = threadIdx.x;
    // p(o) byte offset within a 512B n-row, o = tid
    const unsigned pb = ((unsigned)(tid >> 6) << 7) + ((tid & 15u) << 3)
                      + (((tid >> 4) & 3u) << 1);
    char* slot0 = outb + (size_t)blockIdx.x * spb * 32768;

    float vc[N_NODES];          // converted values for current slot
    unsigned vr[N_NODES];       // raw zext halfwords for next slot

    // prologue: raw-load slot 0
    {
        const char* src = slot0 + pb;
#pragma unroll
        for (int nn = 0; nn < N_NODES; ++nn)
            vr[nn] = *reinterpret_cast<const unsigned short*>(src + nn * 512);
    }

    for (int s = 0; s < spb; ++s) {
        __syncthreads();   // slot-s reads complete block-wide (in-place fence)

        // convert slot s raw -> float (cheap VALU, no memory dependence)
#pragma unroll
        for (int nn = 0; nn < N_NODES; ++nn) {
            union { unsigned u; float f; } cv; cv.u = vr[nn] << 16;
            vc[nn] = cv.f;
        }

        char* cur = slot0 + (size_t)s * 32768;

        // issue slot s+1 raw gathers EARLY (latency hides under compute)
        if (s + 1 < spb) {
            const char* src = cur + 32768 + pb;
#pragma unroll
            for (int nn = 0; nn < N_NODES; ++nn)
                vr[nn] = *reinterpret_cast<const unsigned short*>(src + nn * 512);
        }

        // compute + dense stores for slot s
        float* dst = (float*)cur + tid;
#pragma unroll 4
        for (int m = 0; m < N_NODES; ++m) {
            float sacc = 0.f;
#pragma unroll
            for (int nn = 0; nn < N_NODES; ++nn)
                sacc = fmaf(g[m * N_NODES + nn], vc[nn], sacc);  // uniform s_load
            dst[m * FDIM] = sacc;
        }
    }
}

extern "C" void kernel_launch(void* const* d_in, const int* in_sizes, int n_in,
                              void* d_out, int out_size, void* d_ws, size_t ws_size,
                              hipStream_t stream) {
    const float* input  = (const float*)d_in[0];
    const float* g      = (const float*)d_in[1];
    const int*   ntype  = (const int*)d_in[2];
    const float* weight = (const float*)d_in[3];
    const float* bias   = (const float*)d_in[4];
    char* outb = (char*)d_out;
    __bf16* wp = (__bf16*)d_ws;   // 1 MB

    const int BT = in_sizes[0] / (N_NODES * FDIM);   // 4096

    k0_convert_w<<<N_TYPES * FDIM * FDIM / 256, 256, 0, stream>>>(weight, wp);

    // 256 blocks: n = bx>>3 (32), bt-group = bx&7 (8 x 512 rows)
    k1_node_gemm<<<N_NODES * 8, 256, 0, stream>>>(input, wp, bias, ntype, outb);

    const int spb = (BT + K2_BLOCKS - 1) / K2_BLOCKS;   // 8 for BT=4096
    k2_graph_agg<<<K2_BLOCKS, 256, 0, stream>>>(outb, g, spb);
}

// Round 15
// 81.391 us; speedup vs baseline: 1.8504x; 1.8504x over previous
//
#include <hip/hip_runtime.h>
#include <hip/hip_bf16.h>
#include <stdint.h>

typedef __bf16 bf16x8 __attribute__((ext_vector_type(8)));
typedef __bf16 bf16x4 __attribute__((ext_vector_type(4)));
typedef float f32x4 __attribute__((ext_vector_type(4)));

#define N_NODES 32
#define FDIM 256
#define N_TYPES 8
#define BT_TILE 32
#define TILES 16              // A-tiles per block
#define ROW_B (FDIM * 2)      // 512 B per LDS row (bf16)

// XOR swizzle: row stride 512B puts each k-column in one bank; (row&7)<<4
// spreads 16B slots across 8 positions. Applied on write and read.
__device__ __forceinline__ unsigned swz(unsigned byte_off, unsigned row) {
    return byte_off ^ ((row & 7u) << 4);
}
__device__ __forceinline__ void lds_dma16(void* lds, const void* g) {
    __builtin_amdgcn_global_load_lds(
        (const __attribute__((address_space(1))) unsigned int*)g,
        (__attribute__((address_space(3))) unsigned int*)lds, 16, 0, 0);
}

// ---------------------------------------------------------------------------
// k0: one-time W fp32->bf16, PRE-SWIZZLED full [256 o x 256 k] image per type
// so k1 stages it with linear global_load_lds. Image byte
// L = (o*512 + k*2) ^ ((o&7)<<4) holds W[t][o][k].
// ---------------------------------------------------------------------------
__global__ __launch_bounds__(256) void k0_convert_w(
    const float* __restrict__ w, __bf16* __restrict__ wp)
{
    int idx = blockIdx.x * 256 + threadIdx.x;   // [t][o][k]
    int t = idx >> 16, o = (idx >> 8) & 255, k = idx & 255;
    unsigned L = (unsigned)(o * ROW_B + k * 2) ^ ((o & 7u) << 4);
    wp[(size_t)t * (FDIM * FDIM) + (L >> 1)] = (__bf16)w[idx];
}

// ---------------------------------------------------------------------------
// k1: persistent-W GEMM, R4/R12-EXACT (bf16 epilogue, ~30us = 6.4 TB/s;
// every fp32 epilogue measured 76-94us at this kernel's 1 wave/SIMD).
// Block = (n, bt-group of 512 rows). Full W[t] bf16 in LDS (128 KB, DMA'd
// once); 16 A-tiles [32 x 256], A double-buffered + reg-prefetched one tile
// ahead. Writes out1 bf16 into the FIRST 16 KB of each out[bt] 32KB slot,
// MFMA-frag-permuted: element (bt, n, p), p = wid*64 + lr*4 + nf, at byte
// bt*32768 + n*512 + p*2. 8B/lane contiguous stores. FROZEN.
// ---------------------------------------------------------------------------
__global__ __launch_bounds__(256, 1) void k1_node_gemm(
    const float* __restrict__ input, const __bf16* __restrict__ wp,
    const float* __restrict__ bias, const int* __restrict__ ntype,
    char* __restrict__ outb)
{
    __shared__ __bf16 sW[FDIM * FDIM];          // 131072 B
    __shared__ __bf16 sA[2][BT_TILE * FDIM];    // 2 x 16384 B  (total = 160 KiB)

    const int tid = threadIdx.x;
    const int n = blockIdx.x >> 3;
    const int base = (blockIdx.x & 7) * (TILES * BT_TILE);
    const int t = ntype[n];

    const int wid = tid >> 6, lane = tid & 63;
    const int lr = lane & 15, lq = lane >> 4;
    const int sr = tid >> 3;        // staging row 0..31
    const int sk = tid & 7;         // staging k-octet

    char* sWb = (char*)sW;
    char* sA0 = (char*)sA[0];
    char* sA1 = (char*)sA[1];

    // ---- prologue ----
    const char* wsrc = (const char*)(wp + (size_t)t * (FDIM * FDIM));
#pragma unroll
    for (int j = 0; j < 32; ++j)
        lds_dma16(sWb + j * 4096 + tid * 16, wsrc + j * 4096 + tid * 16);

    float bv[4];
#pragma unroll
    for (int nf = 0; nf < 4; ++nf)
        bv[nf] = bias[t * FDIM + wid * 64 + nf * 16 + lr];

    const char* Abase = (const char*)input
        + ((size_t)(base + sr) * (N_NODES * FDIM) + n * FDIM) * 4 + sk * 16;
    const size_t tile_stride = (size_t)BT_TILE * N_NODES * FDIM * 4;

    float4 av0[8], av1[8];
#pragma unroll
    for (int q = 0; q < 8; ++q)
        av0[q] = *reinterpret_cast<const float4*>(Abase + q * 128);
#pragma unroll
    for (int q = 0; q < 8; ++q)
        av1[q] = *reinterpret_cast<const float4*>(Abase + tile_stride + q * 128);

#pragma unroll
    for (int q = 0; q < 8; ++q) {   // cvt tile0 -> sA0
        bf16x4 h; h[0]=(__bf16)av0[q].x; h[1]=(__bf16)av0[q].y;
        h[2]=(__bf16)av0[q].z; h[3]=(__bf16)av0[q].w;
        *reinterpret_cast<bf16x4*>(sA0 + swz(sr * ROW_B + q * 64 + sk * 8, sr)) = h;
    }
    __syncthreads();   // drains W DMA + A(0) writes

    f32x4 acc[2][4];

#define COMPUTE_TILE(SBUF, TI)                                                  \
    {                                                                           \
        _Pragma("unroll")                                                       \
        for (int mf = 0; mf < 2; ++mf)                                          \
            _Pragma("unroll")                                                   \
            for (int nf = 0; nf < 4; ++nf)                                      \
                acc[mf][nf] = f32x4{0.f, 0.f, 0.f, 0.f};                        \
        _Pragma("unroll")                                                       \
        for (int ks = 0; ks < 8; ++ks) {                                        \
            const int kb = ks * 64 + lq * 16;                                   \
            bf16x8 af[2], bfv[4];                                               \
            _Pragma("unroll")                                                   \
            for (int mf = 0; mf < 2; ++mf) {                                    \
                int r = mf * 16 + lr;                                           \
                af[mf] = *reinterpret_cast<const bf16x8*>(                      \
                    SBUF + swz(r * ROW_B + kb, r));                             \
            }                                                                   \
            _Pragma("unroll")                                                   \
            for (int nf = 0; nf < 4; ++nf) {                                    \
                int o = wid * 64 + nf * 16 + lr;                                \
                bfv[nf] = *reinterpret_cast<const bf16x8*>(                     \
                    sWb + swz(o * ROW_B + kb, o));                              \
            }                                                                   \
            _Pragma("unroll")                                                   \
            for (int mf = 0; mf < 2; ++mf)                                      \
                _Pragma("unroll")                                               \
                for (int nf = 0; nf < 4; ++nf)                                  \
                    acc[mf][nf] = __builtin_amdgcn_mfma_f32_16x16x32_bf16(      \
                        af[mf], bfv[nf], acc[mf][nf], 0, 0, 0);                 \
        }                                                                       \
        /* epilogue: +bias, cvt bf16, frag-permuted coalesced store */          \
        _Pragma("unroll")                                                       \
        for (int mf = 0; mf < 2; ++mf)                                          \
            _Pragma("unroll")                                                   \
            for (int j = 0; j < 4; ++j) {                                       \
                bf16x4 h;                                                       \
                _Pragma("unroll")                                               \
                for (int nf = 0; nf < 4; ++nf)                                  \
                    h[nf] = (__bf16)(acc[mf][nf][j] + bv[nf]);                  \
                size_t bt = (size_t)(base + (TI) * BT_TILE + mf * 16 + lq * 4 + j); \
                *reinterpret_cast<bf16x4*>(outb + bt * 32768 + n * 512          \
                                           + wid * 128 + lr * 8) = h;           \
            }                                                                   \
    }

#define CVT_TO(AV, SDST)                                                        \
    {                                                                           \
        _Pragma("unroll")                                                       \
        for (int q = 0; q < 8; ++q) {                                           \
            bf16x4 h; h[0]=(__bf16)AV[q].x; h[1]=(__bf16)AV[q].y;               \
            h[2]=(__bf16)AV[q].z; h[3]=(__bf16)AV[q].w;                         \
            *reinterpret_cast<bf16x4*>(SDST + swz(sr * ROW_B + q * 64 + sk * 8, \
                                                  sr)) = h;                     \
        }                                                                       \
    }

#define LOAD_TILE(AV, TI)                                                       \
    {                                                                           \
        const char* rp = Abase + (size_t)(TI) * tile_stride;                    \
        _Pragma("unroll")                                                       \
        for (int q = 0; q < 8; ++q)                                             \
            AV[q] = *reinterpret_cast<const float4*>(rp + q * 128);             \
    }

    for (int tt = 0; tt < 8; ++tt) {
        const int e = 2 * tt;
        if (e + 2 < TILES) LOAD_TILE(av0, e + 2);
        COMPUTE_TILE(sA0, e);
        CVT_TO(av1, sA1);
        __syncthreads();
        const int od = 2 * tt + 1;
        if (od + 2 < TILES) LOAD_TILE(av1, od + 2);
        COMPUTE_TILE(sA1, od);
        if (tt < 7) {
            CVT_TO(av0, sA0);
            __syncthreads();
        }
    }
#undef COMPUTE_TILE
#undef CVT_TO
#undef LOAD_TILE
}

// ---------------------------------------------------------------------------
// k2: graph aggregation, in-place slot upgrade bf16 -> fp32. R12-EXACT
// except the stores are NONTEMPORAL.
// Theory (14-round ledger): fast k2s (17-27us) all stored onto lines they
// had just READ (warm in L2); slow k2s (49-63us) store >= half their lines
// COLD (upper slot halves untouched since the poison fill; R10's all-cold
// disjoint-ws k2 was slowest at 63). Suspected L2 fetch-on-write-miss (RFO)
// doubles the effective cost of cold-line stores. nt stores = streaming /
// no-allocate -> bypass the RFO. Reads: direct 2B permuted gathers (64x2B
// per wave in a dense 128B window); g via uniform s_load; 4096 blocks.
// __syncthreads (vmcnt-draining) = in-place fence.
// ---------------------------------------------------------------------------
__global__ __launch_bounds__(256) void k2_graph_agg(
    char* __restrict__ outb, const float* __restrict__ g)
{
    const int tid = threadIdx.x;
    char* slot = outb + (size_t)blockIdx.x * 32768;

    const int o = tid;
    // p(o) = (o>>6)*64 + (o&15)*4 + ((o>>4)&3); byte offset = p*2
    const unsigned pb = ((unsigned)(o >> 6) << 7) + ((o & 15u) << 3)
                      + (((o >> 4) & 3u) << 1);
    const char* src = slot + pb;

    float v[N_NODES];
#pragma unroll
    for (int nn = 0; nn < N_NODES; ++nn) {
        unsigned short hv =
            *reinterpret_cast<const unsigned short*>(src + nn * 512);
        union { unsigned u; float f; } cv; cv.u = (unsigned)hv << 16;
        v[nn] = cv.f;
    }
    __syncthreads();   // all block reads done (vmcnt drained) before writes

    float* dst = (float*)slot + o;
#pragma unroll 4
    for (int m = 0; m < N_NODES; ++m) {
        float s = 0.f;
#pragma unroll
        for (int nn = 0; nn < N_NODES; ++nn)
            s = fmaf(g[m * N_NODES + nn], v[nn], s);   // uniform -> s_load
        __builtin_nontemporal_store(s, dst + m * FDIM);
    }
}

extern "C" void kernel_launch(void* const* d_in, const int* in_sizes, int n_in,
                              void* d_out, int out_size, void* d_ws, size_t ws_size,
                              hipStream_t stream) {
    const float* input  = (const float*)d_in[0];
    const float* g      = (const float*)d_in[1];
    const int*   ntype  = (const int*)d_in[2];
    const float* weight = (const float*)d_in[3];
    const float* bias   = (const float*)d_in[4];
    char* outb = (char*)d_out;
    __bf16* wp = (__bf16*)d_ws;   // 1 MB

    const int BT = in_sizes[0] / (N_NODES * FDIM);   // 4096

    k0_convert_w<<<N_TYPES * FDIM * FDIM / 256, 256, 0, stream>>>(weight, wp);

    // 256 blocks: n = bx>>3 (32), bt-group = bx&7 (8 x 512 rows)
    k1_node_gemm<<<N_NODES * 8, 256, 0, stream>>>(input, wp, bias, ntype, outb);

    k2_graph_agg<<<BT, 256, 0, stream>>>(outb, g);
}